// Round 12
// baseline (66.682 us; speedup 1.0000x reference)
//
#include <hip/hip_runtime.h>

#define HH 56
#define WW 56
#define HWSZ 3136
#define KS 7
#define KK 49

#define XSTR2 264  // x_lds: shorts per c-block row (32px*8c + 8 pad)
#define TSTR 72    // t_lds row stride in shorts
#define WSTR 36    // wgt row stride in shorts (32px + 4 pad)

typedef __attribute__((ext_vector_type(8))) short short8;
typedef __attribute__((ext_vector_type(4))) float f32x4;

__device__ inline unsigned short f2bf(float f) {
    unsigned u = __builtin_bit_cast(unsigned, f);
    u += 0x7FFF + ((u >> 16) & 1);          // RNE
    return (unsigned short)(u >> 16);
}
__device__ inline unsigned pk2(float a, float b) {   // RNE pack
    return (unsigned)f2bf(a) | ((unsigned)f2bf(b) << 16);
}
__device__ inline unsigned pktr(float lo, float hi) { // truncation pack, 1 v_perm
    return __builtin_amdgcn_perm(__builtin_bit_cast(unsigned, hi),
                                 __builtin_bit_cast(unsigned, lo), 0x07060302u);
}
__device__ inline float bflo(unsigned u) { return __builtin_bit_cast(float, u << 16); }
__device__ inline float bfhi(unsigned u) { return __builtin_bit_cast(float, u & 0xFFFF0000u); }

// ---- prep: w2 -> bf16 [16 g][64 kk-padded][64 k], one group per block ----
__global__ __launch_bounds__(256) void kprep(
    const float* __restrict__ w2, unsigned short* __restrict__ w2p)
{
    const int g = blockIdx.x, tid = threadIdx.x;
    #pragma unroll
    for (int it = 0; it < 16; ++it) {
        const int i = it * 256 + tid;
        const int r = i >> 6, k = i & 63;
        float v = (r < KK) ? w2[(g * KK + r) * 64 + k] : 0.f;
        w2p[(size_t)(g * 64 + r) * 64 + k] = f2bf(v);
    }
}

// ---- fused kernel, half-row blocks: grid 3584 = (b,h) x gp x px-half ----
// LDS 21.5 KB -> ~7 blocks/CU (vs 42.5 KB -> 2-3). Phases identical to r11,
// ranges halved. Chunked swizzle: XCD k owns 28 contiguous bh rows.
__global__ __launch_bounds__(256) void fused_dynconv(
    const float* __restrict__ x, const float* __restrict__ y,
    const float* __restrict__ w1, const float* __restrict__ gamma,
    const float* __restrict__ beta, const float* __restrict__ mean,
    const float* __restrict__ var, const unsigned short* __restrict__ w2p,
    const float* __restrict__ b2, float* __restrict__ out)
{
    __shared__ __align__(16) unsigned short lds[32 * XSTR2 + 32 * TSTR]; // 21504 B
    unsigned short* xls = lds;               // [32 cb][32 px][8 c] stride XSTR2
    unsigned short* tls = lds + 32 * XSTR2;  // [32 px][64 o] stride TSTR
    unsigned short* wgt = lds;               // [2 gl][52 kk][36]; aliases xls

    const int tid = threadIdx.x;
    const int lin = (blockIdx.x & 7) * 448 + (blockIdx.x >> 3);  // 0..3583
    const int bh  = lin >> 4;               // 0..223, contiguous per XCD
    const int sub = lin & 15;
    const int gp = sub >> 1, half = sub & 1;
    const int b = bh / HH, h = bh - b * HH;
    const int px0 = h * WW + half * 32;      // global hw of this block's px 0

    // ---- phase 0: stage x[32px][256c] -> bf16 LDS, coalesced float4 reads ----
    {
        const int quad = tid & 7, cs = tid >> 3;         // px-quad 0..7, c-slot 0..31
        const int hwq = min(px0 + quad * 4, HWSZ - 4);   // clamp tail (unused px)
        const float* xb = x + (size_t)b * 256 * HWSZ;
        unsigned short* wbase = xls + quad * 32 + (cs & 3) * 2;
        #pragma unroll
        for (int i = 0; i < 4; ++i) {
            const int c0 = (cs + 32 * i) * 2;            // channel pair
            const int off0 = c0 * HWSZ + hwq;
            float4 va = *(const float4*)(xb + off0);
            float4 vb = *(const float4*)(xb + off0 + HWSZ);
            unsigned short* wp = wbase + ((cs >> 2) + i * 8) * XSTR2;
            *(unsigned*)(wp + 0)  = pktr(va.x, vb.x);
            *(unsigned*)(wp + 8)  = pktr(va.y, vb.y);
            *(unsigned*)(wp + 16) = pktr(va.z, vb.z);
            *(unsigned*)(wp + 24) = pktr(va.w, vb.w);
        }
    }

    const int lane = tid & 63, wv = tid >> 6;
    const int m = lane & 15, q = lane >> 4;

    // A-fragments for GEMM1 from global w1 (L2-hot), trunc pack
    short8 af[8];
    {
        const int wroff = (wv * 16 + m) * 256 + q * 8;
        #pragma unroll
        for (int ks = 0; ks < 8; ++ks) {
            float4 f0 = *(const float4*)(w1 + wroff + ks * 32);
            float4 f1 = *(const float4*)(w1 + wroff + ks * 32 + 4);
            uint4 u = make_uint4(pktr(f0.x, f0.y), pktr(f0.z, f0.w),
                                 pktr(f1.x, f1.y), pktr(f1.z, f1.w));
            af[ks] = __builtin_bit_cast(short8, u);
        }
    }
    __syncthreads();

    // ---- phase 1: GEMM1  t[px][o] = relu(BN(x @ w1^T)), 2 px-subtiles ----
    #pragma unroll
    for (int nt = 0; nt < 2; ++nt) {
        f32x4 acc = {0.f, 0.f, 0.f, 0.f};
        #pragma unroll
        for (int ks = 0; ks < 8; ++ks) {
            short8 bfr = *(const short8*)&xls[(ks * 4 + q) * XSTR2 + (nt * 16 + m) * 8];
            acc = __builtin_amdgcn_mfma_f32_16x16x32_bf16(af[ks], bfr, acc, 0, 0, 0);
        }
        // D: col(lane&15)=px, row((lane>>4)*4+j)=o — verified layout
        const int ob = wv * 16 + q * 4;
        float4 g4 = *(const float4*)&gamma[ob];
        float4 v4 = *(const float4*)&var[ob];
        float4 m4 = *(const float4*)&mean[ob];
        float4 b4 = *(const float4*)&beta[ob];
        float gg[4] = {g4.x, g4.y, g4.z, g4.w};
        float vv[4] = {v4.x, v4.y, v4.z, v4.w};
        float mm[4] = {m4.x, m4.y, m4.z, m4.w};
        float bb[4] = {b4.x, b4.y, b4.z, b4.w};
        float r[4];
        #pragma unroll
        for (int j = 0; j < 4; ++j) {
            float sc = gg[j] * rsqrtf(vv[j] + 1e-5f);
            float sh = bb[j] - mm[j] * sc;
            float val = acc[j] * sc + sh;
            r[j] = val > 0.f ? val : 0.f;
        }
        *(uint2*)&tls[(nt * 16 + m) * TSTR + ob] = make_uint2(pk2(r[0], r[1]), pk2(r[2], r[3]));
    }
    __syncthreads();

    // ---- phase 2: GEMM2  wgt[gl][kk][px] = sum_k t[px][k]*w2p[g][kk][k] + b2 ----
    {
        const int pt = wv & 1, gl = wv >> 1;    // wave = (px-subtile, group)
        const int g = gp * 2 + gl;
        const unsigned short* tp = tls + (pt * 16 + m) * TSTR + q * 8;
        short8 a0 = *(const short8*)tp;            // k = q*8 + 0..7
        short8 a1 = *(const short8*)(tp + 32);     // k = 32 + q*8 + 0..7
        short8 bfr[8];
        #pragma unroll
        for (int mt = 0; mt < 4; ++mt) {
            const int tboff = (g * 64 + mt * 16 + m) * 64 + q * 8;
            bfr[mt * 2]     = *(const short8*)(w2p + tboff);
            bfr[mt * 2 + 1] = *(const short8*)(w2p + tboff + 32);
        }
        f32x4 acc[4];
        #pragma unroll
        for (int mt = 0; mt < 4; ++mt) { acc[mt][0]=0.f; acc[mt][1]=0.f; acc[mt][2]=0.f; acc[mt][3]=0.f; }
        #pragma unroll
        for (int mt = 0; mt < 4; ++mt) {
            acc[mt] = __builtin_amdgcn_mfma_f32_16x16x32_bf16(a0, bfr[mt * 2],     acc[mt], 0, 0, 0);
            acc[mt] = __builtin_amdgcn_mfma_f32_16x16x32_bf16(a1, bfr[mt * 2 + 1], acc[mt], 0, 0, 0);
        }
        // D: col(kk)=lane&15, row(px)=(lane>>4)*4+j — verified layout
        #pragma unroll
        for (int mt = 0; mt < 4; ++mt) {
            const int kk = mt * 16 + m;
            if (kk < 52) {
                float bv = (kk < KK) ? b2[g * KK + kk] : 0.f;
                f32x4 v = acc[mt];
                *(uint2*)&wgt[(gl * 52 + kk) * WSTR + pt * 16 + q * 4] =
                    make_uint2(pk2(v[0] + bv, v[1] + bv), pk2(v[2] + bv, v[3] + bv));
            }
        }
    }
    __syncthreads();

    // ---- phase 3: conv, 1cc x 4px per thread, 1-row-deep pipelined loads ----
    {
        const int gl = tid >> 7;             // 0..1
        const int cc = (tid >> 3) & 15;      // 0..15
        const int pq = tid & 7;              // local px-quad 0..7
        const int pqg = half * 8 + pq;       // global px-quad 0..15
        if (pqg < 14) {
            const int g = gp * 2 + gl;
            const unsigned short* wg = &wgt[gl * 52 * WSTR + pq * 4];
            const bool eL = (pqg > 0), eR = (pqg < 13);
            const int offL = eL ? 0 : 4;     // clamped, always in-bounds
            const int offR = eR ? 8 : 4;
            const float* ybase = y + (size_t)b * 256 * HWSZ;
            const int yoff = (g * 16 + cc) * HWSZ + pqg * 4 - 4;

            float4 cA0, cA1, cA2, nA0, nA1, nA2;
            {
                const int hs = h - 3;
                const int hsc = hs < 0 ? 0 : hs;
                const int r0 = yoff + hsc * WW;
                cA0 = *(const float4*)(ybase + r0 + offL);
                cA1 = *(const float4*)(ybase + r0 + 4);
                cA2 = *(const float4*)(ybase + r0 + offR);
            }
            float a00 = 0.f, a01 = 0.f, a02 = 0.f, a03 = 0.f;

            #pragma unroll
            for (int di = 0; di < KS; ++di) {
                if (di < 6) {                // issue next row's loads first
                    const int hs = h - 2 + di;
                    const int hsc = hs < 0 ? 0 : (hs > HH - 1 ? HH - 1 : hs);
                    const int r0 = yoff + hsc * WW;
                    nA0 = *(const float4*)(ybase + r0 + offL);
                    nA1 = *(const float4*)(ybase + r0 + 4);
                    nA2 = *(const float4*)(ybase + r0 + offR);
                }
                const int hs = h - 3 + di;
                if ((unsigned)hs < HH) {     // block-uniform branch
                    float w0[11];
                    w0[1] = eL ? cA0.y : 0.f;  w0[2] = eL ? cA0.z : 0.f;  w0[3] = eL ? cA0.w : 0.f;
                    w0[4] = cA1.x; w0[5] = cA1.y; w0[6] = cA1.z; w0[7] = cA1.w;
                    w0[8] = eR ? cA2.x : 0.f;  w0[9] = eR ? cA2.y : 0.f;  w0[10] = eR ? cA2.z : 0.f;
                    #pragma unroll
                    for (int dj = 0; dj < KS; ++dj) {
                        uint2 wr = *(const uint2*)&wg[(di * KS + dj) * WSTR];
                        a00 += bflo(wr.x) * w0[dj + 1];
                        a01 += bfhi(wr.x) * w0[dj + 2];
                        a02 += bflo(wr.y) * w0[dj + 3];
                        a03 += bfhi(wr.y) * w0[dj + 4];
                    }
                }
                if (di < 6) { cA0 = nA0; cA1 = nA1; cA2 = nA2; }
            }
            float* o0 = out + (size_t)(b * 256 + g * 16 + cc) * HWSZ + h * WW + pqg * 4;
            *(float4*)o0 = make_float4(a00, a01, a02, a03);
        }
    }
}

extern "C" void kernel_launch(void* const* d_in, const int* in_sizes, int n_in,
                              void* d_out, int out_size, void* d_ws, size_t ws_size,
                              hipStream_t stream) {
    const float* x     = (const float*)d_in[0];
    const float* y     = (const float*)d_in[1];
    const float* w1    = (const float*)d_in[2];
    const float* gamma = (const float*)d_in[3];
    const float* beta  = (const float*)d_in[4];
    const float* mean  = (const float*)d_in[5];
    const float* var   = (const float*)d_in[6];
    const float* w2    = (const float*)d_in[7];
    const float* b2    = (const float*)d_in[8];
    float* out = (float*)d_out;
    unsigned short* w2p = (unsigned short*)d_ws;   // [16*64][64] bf16, 128 KB

    kprep<<<16, 256, 0, stream>>>(w2, w2p);
    fused_dynconv<<<3584, 256, 0, stream>>>(x, y, w1, gamma, beta, mean, var, w2p, b2, out);
}

// Round 13
// 47.018 us; speedup vs baseline: 1.4182x; 1.4182x over previous
//
#include <hip/hip_runtime.h>

#define HH 56
#define WW 56
#define HWSZ 3136
#define KS 7
#define KK 49

#define XS3 136   // ka xls stride in shorts: 16px*8c + 8 pad
#define TBS 72    // ka tbuf stride in shorts (rows 144B, 16B-aligned)

typedef __attribute__((ext_vector_type(8))) short short8;
typedef __attribute__((ext_vector_type(4))) float f32x4;

__device__ inline unsigned short f2bf(float f) {
    unsigned u = __builtin_bit_cast(unsigned, f);
    u += 0x7FFF + ((u >> 16) & 1);          // RNE
    return (unsigned short)(u >> 16);
}
__device__ inline unsigned pk2(float a, float b) {   // RNE pack
    return (unsigned)f2bf(a) | ((unsigned)f2bf(b) << 16);
}
__device__ inline unsigned pktr(float lo, float hi) { // truncation pack, 1 v_perm
    return __builtin_amdgcn_perm(__builtin_bit_cast(unsigned, hi),
                                 __builtin_bit_cast(unsigned, lo), 0x07060302u);
}
__device__ inline float bflo(unsigned u) { return __builtin_bit_cast(float, u << 16); }
__device__ inline float bfhi(unsigned u) { return __builtin_bit_cast(float, u & 0xFFFF0000u); }

// ---- prep: w2 -> bf16 [16 g][64 kk-pad][64 k]; w1 -> bf16 [64 o][256 c] ----
__global__ __launch_bounds__(256) void kprep(
    const float* __restrict__ w2, const float* __restrict__ w1,
    unsigned short* __restrict__ w2p, unsigned short* __restrict__ w1p)
{
    const int tid = threadIdx.x;
    if (blockIdx.x < 16) {
        const int g = blockIdx.x;
        #pragma unroll
        for (int it = 0; it < 16; ++it) {
            const int i = it * 256 + tid;
            const int r = i >> 6, k = i & 63;
            float v = (r < KK) ? w2[(g * KK + r) * 64 + k] : 0.f;
            w2p[(g * 64 + r) * 64 + k] = f2bf(v);
        }
    } else {
        const int qb = blockIdx.x - 16;      // w1 quarter (4096 floats each)
        #pragma unroll
        for (int it = 0; it < 4; ++it) {
            const int idx = qb * 4096 + (it * 256 + tid) * 4;
            float4 v = *(const float4*)(w1 + idx);
            *(uint2*)(w1p + idx) = make_uint2(pk2(v.x, v.y), pk2(v.z, v.w));
        }
    }
}

// ---- ka16: t[p][64] = relu(BN(x @ w1^T)) bf16; 784 blocks x 16-px tiles ----
__global__ __launch_bounds__(256) void ka16(
    const float* __restrict__ x, const float* __restrict__ gamma,
    const float* __restrict__ beta, const float* __restrict__ mean,
    const float* __restrict__ var, const unsigned short* __restrict__ w1p,
    unsigned short* __restrict__ t_bf)
{
    __shared__ __align__(16) unsigned short xls[32 * XS3];   // 8.7 KB
    __shared__ __align__(16) unsigned short tbuf[16 * TBS];  // 2.3 KB

    const int tid = threadIdx.x;
    const int p0 = blockIdx.x * 16;          // 3136 % 16 == 0: tiles never cross b
    const int b = p0 / HWSZ, hw0 = p0 - b * HWSZ;

    // stage x[16px][256c] -> bf16 LDS, coalesced float4 reads, 4 loads/thread
    {
        const int quad = tid & 3, cs = tid >> 2;            // px-quad, c-slot
        const int base = b * 256 * HWSZ + hw0 + quad * 4;   // 32-bit offset
        #pragma unroll
        for (int i = 0; i < 2; ++i) {
            const int cp = cs + 64 * i;                     // channel pair id
            const int off = (cp * 2) * HWSZ + base;
            float4 va = *(const float4*)(x + off);
            float4 vb = *(const float4*)(x + off + HWSZ);
            unsigned short* wp = xls + (cp >> 2) * XS3 + quad * 32 + (cp & 3) * 2;
            *(unsigned*)(wp + 0)  = pktr(va.x, vb.x);
            *(unsigned*)(wp + 8)  = pktr(va.y, vb.y);
            *(unsigned*)(wp + 16) = pktr(va.z, vb.z);
            *(unsigned*)(wp + 24) = pktr(va.w, vb.w);
        }
    }

    const int lane = tid & 63, wv = tid >> 6;
    const int m = lane & 15, q = lane >> 4;

    // A-fragments: 8 plain short8 loads from w1p (bf16, L2-hot)
    short8 af[8];
    {
        const int woff = (wv * 16 + m) * 256 + q * 8;
        #pragma unroll
        for (int ks = 0; ks < 8; ++ks)
            af[ks] = *(const short8*)(w1p + woff + ks * 32);
    }
    __syncthreads();

    // GEMM1: wave wv owns o-tile; single 16-px n-tile
    f32x4 acc = {0.f, 0.f, 0.f, 0.f};
    #pragma unroll
    for (int ks = 0; ks < 8; ++ks) {
        short8 bfr = *(const short8*)&xls[(ks * 4 + q) * XS3 + m * 8];
        acc = __builtin_amdgcn_mfma_f32_16x16x32_bf16(af[ks], bfr, acc, 0, 0, 0);
    }
    // D: col(lane&15)=px, row((lane>>4)*4+j)=o — verified layout
    {
        const int ob = wv * 16 + q * 4;
        float4 g4 = *(const float4*)&gamma[ob];
        float4 v4 = *(const float4*)&var[ob];
        float4 m4 = *(const float4*)&mean[ob];
        float4 b4 = *(const float4*)&beta[ob];
        float gg[4] = {g4.x, g4.y, g4.z, g4.w};
        float vv[4] = {v4.x, v4.y, v4.z, v4.w};
        float mm[4] = {m4.x, m4.y, m4.z, m4.w};
        float bb[4] = {b4.x, b4.y, b4.z, b4.w};
        float r[4];
        #pragma unroll
        for (int j = 0; j < 4; ++j) {
            float sc = gg[j] * rsqrtf(vv[j] + 1e-5f);
            float sh = bb[j] - mm[j] * sc;
            float val = acc[j] * sc + sh;
            r[j] = val > 0.f ? val : 0.f;
        }
        *(uint2*)&tbuf[m * TBS + ob] = make_uint2(pk2(r[0], r[1]), pk2(r[2], r[3]));
    }
    __syncthreads();

    // coalesced t store: 128 threads x uint4, 128B per px row
    if (tid < 128) {
        const int px = tid >> 3, seg = tid & 7;
        uint4 v = *(const uint4*)&tbuf[px * TBS + seg * 8];
        *(uint4*)&t_bf[(p0 + px) * 64 + seg * 8] = v;
    }
}

// ---- kb: GEMM2 (2 groups) + pipelined dynamic conv; grid 1792, chunked swizzle ----
__global__ __launch_bounds__(256) void kb(
    const float* __restrict__ y, const float* __restrict__ b2,
    const unsigned short* __restrict__ t_bf, const unsigned short* __restrict__ w2p,
    float* __restrict__ out)
{
    __shared__ __align__(16) unsigned short wgt[2 * 52 * 68];   // 14.1 KB

    const int tid = threadIdx.x;
    const int lin = (blockIdx.x & 7) * 224 + (blockIdx.x >> 3);
    const int bh = lin >> 3, gp = lin & 7;
    const int b = bh / HH, h = bh - b * HH;
    const int p0 = b * HWSZ + h * WW;

    const int lane = tid & 63, wv = tid >> 6;
    const int m = lane & 15, q = lane >> 4;

    // GEMM2: wave = pixel-tile; t from global (L2-hot)
    {
        const unsigned short* ta = t_bf + (p0 + wv * 16 + m) * 64 + q * 8;
        short8 a0 = *(const short8*)ta;
        short8 a1 = *(const short8*)(ta + 32);
        #pragma unroll
        for (int it = 0; it < 2; ++it) {
            const int g = gp * 2 + it;
            short8 bfr[8];
            #pragma unroll
            for (int mt = 0; mt < 4; ++mt) {
                const int tboff = (g * 64 + mt * 16 + m) * 64 + q * 8;
                bfr[mt * 2]     = *(const short8*)(w2p + tboff);
                bfr[mt * 2 + 1] = *(const short8*)(w2p + tboff + 32);
            }
            f32x4 acc[4];
            #pragma unroll
            for (int mt = 0; mt < 4; ++mt) { acc[mt][0]=0.f; acc[mt][1]=0.f; acc[mt][2]=0.f; acc[mt][3]=0.f; }
            #pragma unroll
            for (int mt = 0; mt < 4; ++mt) {
                acc[mt] = __builtin_amdgcn_mfma_f32_16x16x32_bf16(a0, bfr[mt * 2],     acc[mt], 0, 0, 0);
                acc[mt] = __builtin_amdgcn_mfma_f32_16x16x32_bf16(a1, bfr[mt * 2 + 1], acc[mt], 0, 0, 0);
            }
            // D: col(kk)=lane&15, row(px)=(lane>>4)*4+j — verified layout
            #pragma unroll
            for (int mt = 0; mt < 4; ++mt) {
                const int kk = mt * 16 + m;
                if (kk < 52) {
                    float bv = (kk < KK) ? b2[g * KK + kk] : 0.f;
                    f32x4 v = acc[mt];
                    *(uint2*)&wgt[(it * 52 + kk) * 68 + wv * 16 + q * 4] =
                        make_uint2(pk2(v[0] + bv, v[1] + bv), pk2(v[2] + bv, v[3] + bv));
                }
            }
        }
    }
    __syncthreads();

    // conv: 2cc x 4px per thread, 1-row-deep pipelined loads
    if (tid < 224) {
        const int gl = tid / 112;
        const int rem = tid - gl * 112;
        const int c2 = rem / 14, pq = rem - c2 * 14;
        const int cc0 = c2 * 2;
        const unsigned short* wg = &wgt[gl * 52 * 68 + pq * 4];
        const bool eL = (pq > 0), eR = (pq < 13);
        const int offL = eL ? 0 : 4;
        const int offR = eR ? 8 : 4;
        const float* ybase = y + (size_t)b * 256 * HWSZ;
        const int yoff = (gp * 32 + gl * 16 + cc0) * HWSZ + pq * 4 - 4;

        float4 cA0, cA1, cA2, cB0, cB1, cB2;
        float4 nA0, nA1, nA2, nB0, nB1, nB2;
        {
            const int hs = h - 3;
            const int hsc = hs < 0 ? 0 : hs;
            const int r0 = yoff + hsc * WW;
            cA0 = *(const float4*)(ybase + r0 + offL);
            cA1 = *(const float4*)(ybase + r0 + 4);
            cA2 = *(const float4*)(ybase + r0 + offR);
            cB0 = *(const float4*)(ybase + r0 + HWSZ + offL);
            cB1 = *(const float4*)(ybase + r0 + HWSZ + 4);
            cB2 = *(const float4*)(ybase + r0 + HWSZ + offR);
        }
        float a00=0.f,a01=0.f,a02=0.f,a03=0.f;
        float a10=0.f,a11=0.f,a12=0.f,a13=0.f;

        #pragma unroll
        for (int di = 0; di < KS; ++di) {
            if (di < 6) {
                const int hs = h - 2 + di;
                const int hsc = hs < 0 ? 0 : (hs > HH - 1 ? HH - 1 : hs);
                const int r0 = yoff + hsc * WW;
                nA0 = *(const float4*)(ybase + r0 + offL);
                nA1 = *(const float4*)(ybase + r0 + 4);
                nA2 = *(const float4*)(ybase + r0 + offR);
                nB0 = *(const float4*)(ybase + r0 + HWSZ + offL);
                nB1 = *(const float4*)(ybase + r0 + HWSZ + 4);
                nB2 = *(const float4*)(ybase + r0 + HWSZ + offR);
            }
            const int hs = h - 3 + di;
            if ((unsigned)hs < HH) {
                float w0[11], w1v[11];
                w0[1] = eL ? cA0.y : 0.f;  w0[2] = eL ? cA0.z : 0.f;  w0[3] = eL ? cA0.w : 0.f;
                w0[4] = cA1.x; w0[5] = cA1.y; w0[6] = cA1.z; w0[7] = cA1.w;
                w0[8] = eR ? cA2.x : 0.f;  w0[9] = eR ? cA2.y : 0.f;  w0[10] = eR ? cA2.z : 0.f;
                w1v[1] = eL ? cB0.y : 0.f; w1v[2] = eL ? cB0.z : 0.f; w1v[3] = eL ? cB0.w : 0.f;
                w1v[4] = cB1.x; w1v[5] = cB1.y; w1v[6] = cB1.z; w1v[7] = cB1.w;
                w1v[8] = eR ? cB2.x : 0.f; w1v[9] = eR ? cB2.y : 0.f; w1v[10] = eR ? cB2.z : 0.f;
                #pragma unroll
                for (int dj = 0; dj < KS; ++dj) {
                    uint2 wr = *(const uint2*)&wg[(di * KS + dj) * 68];
                    float g0 = bflo(wr.x), g1 = bfhi(wr.x);
                    float g2 = bflo(wr.y), g3 = bfhi(wr.y);
                    a00 += g0 * w0[dj + 1];  a01 += g1 * w0[dj + 2];
                    a02 += g2 * w0[dj + 3];  a03 += g3 * w0[dj + 4];
                    a10 += g0 * w1v[dj + 1]; a11 += g1 * w1v[dj + 2];
                    a12 += g2 * w1v[dj + 3]; a13 += g3 * w1v[dj + 4];
                }
            }
            if (di < 6) {
                cA0 = nA0; cA1 = nA1; cA2 = nA2;
                cB0 = nB0; cB1 = nB1; cB2 = nB2;
            }
        }
        float* o0 = out + (size_t)(b * 256 + gp * 32 + gl * 16 + cc0) * HWSZ + h * WW + pq * 4;
        *(float4*)o0 = make_float4(a00, a01, a02, a03);
        *(float4*)(o0 + HWSZ) = make_float4(a10, a11, a12, a13);
    }
}

extern "C" void kernel_launch(void* const* d_in, const int* in_sizes, int n_in,
                              void* d_out, int out_size, void* d_ws, size_t ws_size,
                              hipStream_t stream) {
    const float* x     = (const float*)d_in[0];
    const float* y     = (const float*)d_in[1];
    const float* w1    = (const float*)d_in[2];
    const float* gamma = (const float*)d_in[3];
    const float* beta  = (const float*)d_in[4];
    const float* mean  = (const float*)d_in[5];
    const float* var   = (const float*)d_in[6];
    const float* w2    = (const float*)d_in[7];
    const float* b2    = (const float*)d_in[8];
    float* out = (float*)d_out;

    unsigned short* t_bf = (unsigned short*)d_ws;        // [12544][64] bf16
    unsigned short* w2p  = t_bf + 12544 * 64;            // [16*64][64] bf16
    unsigned short* w1p  = w2p + 16 * 64 * 64;           // [64][256] bf16

    kprep<<<20, 256, 0, stream>>>(w2, w1, w2p, w1p);
    ka16 <<<784, 256, 0, stream>>>(x, gamma, beta, mean, var, w1p, t_bf);
    kb   <<<1792, 256, 0, stream>>>(y, b2, t_bf, w2p, out);
}